// Round 1
// baseline (326.891 us; speedup 1.0000x reference)
//
#include <hip/hip_runtime.h>
#include <hip/hip_bf16.h>
#include <stdint.h>

// Problem constants
static constexpr int cN    = 4096;
static constexpr int cHID  = 256;
static constexpr int cTASK = 128;
static constexpr int cL    = 2;

typedef short bf16x8 __attribute__((ext_vector_type(8)));
typedef float f32x4  __attribute__((ext_vector_type(4)));

#define MFMA(a, b, c) __builtin_amdgcn_mfma_f32_16x16x32_bf16((a), (b), (c), 0, 0, 0)

static __device__ __forceinline__ uint16_t f2bf(float f) {
    uint32_t u = __float_as_uint(f);
    uint32_t r = (u + 0x7FFFu + ((u >> 16) & 1u)) >> 16;
    return (uint16_t)r;
}
static __device__ __forceinline__ float bf2f(uint16_t h) {
    return __uint_as_float(((uint32_t)h) << 16);
}
static __device__ __forceinline__ bf16x8 ld_frag(const uint16_t* p) {
    return *reinterpret_cast<const bf16x8*>(p);  // 16B aligned by construction
}

// ---------------- casts: h, z to bf16; weights to transposed bf16 ----------------
__global__ __launch_bounds__(256) void k_cast(const float* __restrict__ h,
                                              const float* __restrict__ z,
                                              const float* __restrict__ Wp,
                                              const float* __restrict__ Wm,
                                              const float* __restrict__ Wg,
                                              uint16_t* __restrict__ hin_bf,
                                              uint16_t* __restrict__ z_bf,
                                              uint16_t* __restrict__ WpT,
                                              uint16_t* __restrict__ WmT,
                                              uint16_t* __restrict__ WgT) {
    int idx = blockIdx.x * 256 + threadIdx.x;
    if (idx < cN * cHID) { hin_bf[idx] = f2bf(h[idx]); return; }
    idx -= cN * cHID;
    if (idx < cN * cTASK) { z_bf[idx] = f2bf(z[idx]); return; }
    idx -= cN * cTASK;
    if (idx < cHID * cHID) {                    // WpT[d][k] = Wp[k][d]
        int d = idx >> 8, k = idx & 255;
        WpT[idx] = f2bf(Wp[k * 256 + d]); return;
    }
    idx -= cHID * cHID;
    if (idx < cL * cHID * cHID) {               // WmT[l][d][k] = Wm[l][k][d]
        int l = idx >> 16, r = idx & 65535;
        int d = r >> 8, k = r & 255;
        WmT[idx] = f2bf(Wm[l * 65536 + k * 256 + d]); return;
    }
    idx -= cL * cHID * cHID;
    if (idx < cL * cHID * 384) {                // WgT[l][d][k384] = Wg[l][k][d]
        int l = idx / 98304, r = idx % 98304;
        int d = r / 384, k = r % 384;
        WgT[idx] = f2bf(Wg[l * 98304 + k * 256 + d]); return;
    }
}

// ---------------- adj -> bitmask (2 MiB) ----------------
__global__ __launch_bounds__(256) void k_bits(const int* __restrict__ adj,
                                              uint32_t* __restrict__ maskw) {
    int i = blockIdx.x;
    int wid = threadIdx.x >> 6, lane = threadIdx.x & 63;
    const int* row = adj + (size_t)i * cN;
    for (int base = wid * 64; base < cN; base += 256) {
        int v = row[base + lane];
        unsigned long long b = __ballot(v > 0);
        if (lane == 0)  maskw[i * 128 + (base >> 5)]     = (uint32_t)b;
        if (lane == 32) maskw[i * 128 + (base >> 5) + 1] = (uint32_t)(b >> 32);
    }
}

// ---------------- folded attention vectors: wqv = Wq@a_q, wkv = Wk@a_k, cq, ck ----------------
__global__ __launch_bounds__(256) void k_wvec(const float* __restrict__ Wq,
                                              const float* __restrict__ bq,
                                              const float* __restrict__ Wk,
                                              const float* __restrict__ bk,
                                              const float* __restrict__ a,
                                              float* __restrict__ wqv,
                                              float* __restrict__ wkv,
                                              float* __restrict__ cvec) {
    int l = blockIdx.x >> 1, which = blockIdx.x & 1;  // which: 0=q, 1=k
    int d = threadIdx.x;
    const float* W    = which ? (Wk + l * 65536) : (Wq + l * 65536);
    const float* avec = a + l * 512 + (which ? 0 : 256);
    const float* bias = which ? (bk + l * 256) : (bq + l * 256);
    float s = 0.f;
    for (int o = 0; o < 256; ++o) s += W[d * 256 + o] * avec[o];
    (which ? wkv : wqv)[l * 256 + d] = s;
    __shared__ float red[256];
    red[d] = bias[d] * avec[d];
    __syncthreads();
    for (int off = 128; off > 0; off >>= 1) {
        if (d < off) red[d] += red[d + off];
        __syncthreads();
    }
    if (d == 0) cvec[blockIdx.x] = red[0];  // cvec[l*2 + which]
}

// ---------------- initial projection: h = hin @ Wp + bp ----------------
__global__ __launch_bounds__(256) void k_proj(const uint16_t* __restrict__ hin_bf,
                                              const uint16_t* __restrict__ WpT,
                                              const float* __restrict__ bp,
                                              float* __restrict__ h_f32,
                                              uint16_t* __restrict__ hcur_bf) {
    int bx = blockIdx.x, by = blockIdx.y;
    int tid = threadIdx.x, lane = tid & 63, wid = tid >> 6;
    int wr = wid >> 1, wc = wid & 1;
    int l16 = lane & 15, g = lane >> 4;
    int i0 = bx * 64 + wr * 32, d0 = by * 64 + wc * 32;
    f32x4 acc[2][2] = {};
#pragma unroll
    for (int ks = 0; ks < 8; ++ks) {
        int kb = ks * 32 + g * 8;
        bf16x8 afr[2], bfr[2];
#pragma unroll
        for (int mr = 0; mr < 2; ++mr) afr[mr] = ld_frag(hin_bf + (size_t)(i0 + mr * 16 + l16) * 256 + kb);
#pragma unroll
        for (int nr = 0; nr < 2; ++nr) bfr[nr] = ld_frag(WpT + (size_t)(d0 + nr * 16 + l16) * 256 + kb);
#pragma unroll
        for (int mr = 0; mr < 2; ++mr)
#pragma unroll
            for (int nr = 0; nr < 2; ++nr)
                acc[mr][nr] = MFMA(afr[mr], bfr[nr], acc[mr][nr]);
    }
#pragma unroll
    for (int mr = 0; mr < 2; ++mr)
#pragma unroll
        for (int nr = 0; nr < 2; ++nr) {
            int d = d0 + nr * 16 + l16;
            float bias = bp[d];
#pragma unroll
            for (int r = 0; r < 4; ++r) {
                int i = i0 + mr * 16 + g * 4 + r;
                float v = acc[mr][nr][r] + bias;
                h_f32[(size_t)i * 256 + d] = v;
                hcur_bf[(size_t)i * 256 + d] = f2bf(v);
            }
        }
}

// ---------------- fused message+gate GEMM; writes gmT (bf16, [d][i]); gate L1 sum ----------------
__global__ __launch_bounds__(256) void k_msgg(const uint16_t* __restrict__ hcur_bf,
                                              const uint16_t* __restrict__ z_bf,
                                              const uint16_t* __restrict__ WmT,
                                              const uint16_t* __restrict__ WgT,
                                              const float* __restrict__ bm,
                                              const float* __restrict__ bg,
                                              uint16_t* __restrict__ gmT,
                                              float* __restrict__ gsum,
                                              int layer) {
    int bx = blockIdx.x, by = blockIdx.y;
    int tid = threadIdx.x, lane = tid & 63, wid = tid >> 6;
    int wr = wid >> 1, wc = wid & 1;
    int l16 = lane & 15, g = lane >> 4;
    int i0 = bx * 64 + wr * 32, d0 = by * 64 + wc * 32;
    const uint16_t* WmTl = WmT + layer * 65536;
    const uint16_t* WgTl = WgT + layer * 98304;
    f32x4 am[2][2] = {}, ag[2][2] = {};
#pragma unroll
    for (int ks = 0; ks < 8; ++ks) {
        int kb = ks * 32 + g * 8;
        bf16x8 afr[2], bmf[2], bgf[2];
#pragma unroll
        for (int mr = 0; mr < 2; ++mr) afr[mr] = ld_frag(hcur_bf + (size_t)(i0 + mr * 16 + l16) * 256 + kb);
#pragma unroll
        for (int nr = 0; nr < 2; ++nr) {
            bmf[nr] = ld_frag(WmTl + (size_t)(d0 + nr * 16 + l16) * 256 + kb);
            bgf[nr] = ld_frag(WgTl + (size_t)(d0 + nr * 16 + l16) * 384 + kb);
        }
#pragma unroll
        for (int mr = 0; mr < 2; ++mr)
#pragma unroll
            for (int nr = 0; nr < 2; ++nr) {
                am[mr][nr] = MFMA(afr[mr], bmf[nr], am[mr][nr]);
                ag[mr][nr] = MFMA(afr[mr], bgf[nr], ag[mr][nr]);
            }
    }
#pragma unroll
    for (int ks = 0; ks < 4; ++ks) {   // z part of concat: k = 256..383
        int kb = ks * 32 + g * 8;
        bf16x8 afr[2], bgf[2];
#pragma unroll
        for (int mr = 0; mr < 2; ++mr) afr[mr] = ld_frag(z_bf + (size_t)(i0 + mr * 16 + l16) * 128 + kb);
#pragma unroll
        for (int nr = 0; nr < 2; ++nr) bgf[nr] = ld_frag(WgTl + (size_t)(d0 + nr * 16 + l16) * 384 + 256 + kb);
#pragma unroll
        for (int mr = 0; mr < 2; ++mr)
#pragma unroll
            for (int nr = 0; nr < 2; ++nr)
                ag[mr][nr] = MFMA(afr[mr], bgf[nr], ag[mr][nr]);
    }
    float gs = 0.f;
#pragma unroll
    for (int mr = 0; mr < 2; ++mr)
#pragma unroll
        for (int nr = 0; nr < 2; ++nr) {
            int d = d0 + nr * 16 + l16;
            float bmv = bm[layer * 256 + d], bgv = bg[layer * 256 + d];
            ushort4 pack;
#pragma unroll
            for (int r = 0; r < 4; ++r) {
                float rm = am[mr][nr][r] + bmv; rm = rm > 0.f ? rm : 0.f;
                float gt = 1.f / (1.f + __expf(-(ag[mr][nr][r] + bgv)));
                gs += gt;
                float gmv = gt * rm;
                ((uint16_t*)&pack)[r] = f2bf(gmv);
            }
            int i = i0 + mr * 16 + g * 4;
            *reinterpret_cast<ushort4*>(gmT + (size_t)d * cN + i) = pack;
        }
    for (int off = 32; off; off >>= 1) gs += __shfl_down(gs, off, 64);
    __shared__ float wred[4];
    if (lane == 0) wred[wid] = gs;
    __syncthreads();
    if (tid == 0) atomicAdd(gsum, wred[0] + wred[1] + wred[2] + wred[3]);
}

// ---------------- qq[i] = gm[i,:] . wqv + cq   (gmT is [d][i] -> coalesced over i) ----------------
__global__ __launch_bounds__(256) void k_qq(const uint16_t* __restrict__ gmT,
                                            const float* __restrict__ wqv,
                                            const float* __restrict__ cvec,
                                            float* __restrict__ qq, int layer) {
    int i = blockIdx.x * 256 + threadIdx.x;
    const float* wv = wqv + layer * 256;
    float s = cvec[layer * 2 + 0];
    for (int d = 0; d < 256; ++d) s += bf2f(gmT[(size_t)d * cN + i]) * wv[d];
    qq[i] = s;
}

// ---------------- kk[i] = h[i,:] . wkv + ck  (wave per row) ----------------
__global__ __launch_bounds__(256) void k_kk(const uint16_t* __restrict__ hcur_bf,
                                            const float* __restrict__ wkv,
                                            const float* __restrict__ cvec,
                                            float* __restrict__ kk, int layer) {
    int wid = threadIdx.x >> 6, lane = threadIdx.x & 63;
    int i = blockIdx.x * 4 + wid;
    const float* wv = wkv + layer * 256;
    float s = 0.f;
#pragma unroll
    for (int c = 0; c < 4; ++c) {
        int k = c * 64 + lane;
        s += bf2f(hcur_bf[(size_t)i * 256 + k]) * wv[k];
    }
    for (int off = 32; off; off >>= 1) s += __shfl_down(s, off, 64);
    if (lane == 0) kk[i] = s + cvec[layer * 2 + 1];
}

// ---------------- per-row softmax stats: stats4[i] = (qq, m, 1/den, 0) ----------------
__global__ __launch_bounds__(256) void k_stats(const float* __restrict__ qq,
                                               const float* __restrict__ kk,
                                               const uint32_t* __restrict__ maskw,
                                               float4* __restrict__ stats4) {
    __shared__ float kks[cN];
    for (int t = threadIdx.x; t < cN / 4; t += 256)
        reinterpret_cast<float4*>(kks)[t] = reinterpret_cast<const float4*>(kk)[t];
    __syncthreads();
    int wid = threadIdx.x >> 6, lane = threadIdx.x & 63;
    int i = blockIdx.x * 4 + wid;
    float qqi = qq[i];
    const uint32_t* mrow = maskw + i * 128;
    float kmax = -1e30f;
    for (int c = 0; c < 64; ++c) {
        int j = c * 64 + lane;
        uint32_t w = mrow[j >> 5];
        bool on = (w >> (j & 31)) & 1;
        float kv = kks[j];
        if (on && kv > kmax) kmax = kv;
    }
    for (int off = 32; off; off >>= 1) { float o = __shfl_down(kmax, off, 64); if (o > kmax) kmax = o; }
    kmax = __shfl(kmax, 0, 64);
    float e0 = qqi + kmax;
    float m = e0 > 0.f ? e0 : 0.01f * e0;   // leaky_relu monotone -> row max
    float den = 0.f;
    for (int c = 0; c < 64; ++c) {
        int j = c * 64 + lane;
        uint32_t w = mrow[j >> 5];
        bool on = (w >> (j & 31)) & 1;
        float e = qqi + kks[j];
        e = e > 0.f ? e : 0.01f * e;
        den += on ? __expf(e - m) : 0.f;
    }
    for (int off = 32; off; off >>= 1) den += __shfl_down(den, off, 64);
    if (lane == 0) {
        float rden = den > 0.f ? 1.f / den : 0.f;
        stats4[i] = make_float4(qqi, m, rden, 0.f);
    }
}

// ---------------- agg = attention^T @ gm  (flash-style; w computed on the fly) ----------------
// grid (256 j-tiles, NSEG); block 256 = 4 waves, wave owns a 64-wide d-quarter.
__global__ __launch_bounds__(256) void k_agg(const uint16_t* __restrict__ gmT,
                                             const float4* __restrict__ stats4,
                                             const uint32_t* __restrict__ maskw,
                                             const float* __restrict__ kk,
                                             float* __restrict__ part, int nseg) {
    constexpr int ASTRIDE = 136;  // 16B-aligned, conflict-light for ds_read_b128
    __shared__ uint16_t A_lds[16 * ASTRIDE];
    int jt = blockIdx.x, seg = blockIdx.y;
    int jt0 = jt * 16;
    int tid = threadIdx.x, lane = tid & 63, wid = tid >> 6;
    int l16 = lane & 15, g = lane >> 4;
    int dq0 = wid * 64;
    // w-compute assignment: thread -> (jj = tid&15, 8 consecutive i)
    int jj = tid & 15;
    int iofs = (tid >> 4) * 8;
    float kkj = kk[jt0 + jj];
    int wordIdx = jt0 >> 5;
    int shift = (jt0 & 31) + jj;
    f32x4 acc[4] = {};
    int kseg = cN / nseg;
    int ib0 = seg * kseg;
    for (int s = 0; s < kseg / 128; ++s) {
        int ibase = ib0 + s * 128;
        __syncthreads();  // previous stage's A_lds reads done
        uint16_t wb[8];
#pragma unroll
        for (int u = 0; u < 8; ++u) {
            int i = ibase + iofs + u;
            float4 st = stats4[i];
            uint32_t wrd = maskw[i * 128 + wordIdx];
            bool on = (wrd >> shift) & 1;
            float e = st.x + kkj;
            e = e > 0.f ? e : 0.01f * e;
            float w = on ? __expf(e - st.y) * st.z : 0.f;
            wb[u] = f2bf(w);
        }
        *reinterpret_cast<uint4*>(&A_lds[jj * ASTRIDE + iofs]) = *reinterpret_cast<uint4*>(wb);
        __syncthreads();
#pragma unroll
        for (int ksub = 0; ksub < 4; ++ksub) {
            int kb = ksub * 32;
            bf16x8 afr = ld_frag(&A_lds[l16 * ASTRIDE + kb + g * 8]);
            int ig = ibase + kb + g * 8;
#pragma unroll
            for (int nr = 0; nr < 4; ++nr) {
                bf16x8 bfr = ld_frag(gmT + (size_t)(dq0 + nr * 16 + l16) * cN + ig);
                acc[nr] = MFMA(afr, bfr, acc[nr]);
            }
        }
    }
#pragma unroll
    for (int nr = 0; nr < 4; ++nr) {
        int d = dq0 + nr * 16 + l16;
#pragma unroll
        for (int r = 0; r < 4; ++r) {
            int j = jt0 + g * 4 + r;
            part[((size_t)seg * cN + j) * 256 + d] = acc[nr][r];
        }
    }
}

// ---------------- residual: h = (sum(parts) + h)/2; refresh bf16 mirror; maybe emit output ----------------
__global__ __launch_bounds__(256) void k_resid(const float* __restrict__ part,
                                               float* __restrict__ h_f32,
                                               uint16_t* __restrict__ hcur_bf,
                                               float* __restrict__ out,
                                               int nseg, int last) {
    int idx = blockIdx.x * 256 + threadIdx.x;   // float4 index over 1M floats
    float4 acc = reinterpret_cast<float4*>(h_f32)[idx];
    for (int p = 0; p < nseg; ++p) {
        float4 v = reinterpret_cast<const float4*>(part + (size_t)p * cN * 256)[idx];
        acc.x += v.x; acc.y += v.y; acc.z += v.z; acc.w += v.w;
    }
    acc.x *= 0.5f; acc.y *= 0.5f; acc.z *= 0.5f; acc.w *= 0.5f;
    reinterpret_cast<float4*>(h_f32)[idx] = acc;
    ushort4 hb; hb.x = f2bf(acc.x); hb.y = f2bf(acc.y); hb.z = f2bf(acc.z); hb.w = f2bf(acc.w);
    reinterpret_cast<ushort4*>(hcur_bf)[idx] = hb;
    if (last) reinterpret_cast<float4*>(out)[idx] = acc;
}

__global__ void k_fin(const float* __restrict__ gsum, float* __restrict__ out) {
    out[(size_t)cN * cHID] = gsum[0] * (1.f / ((float)(cN * cHID) * (float)cL));
}

// ---------------- host side ----------------
extern "C" void kernel_launch(void* const* d_in, const int* in_sizes, int n_in,
                              void* d_out, int out_size, void* d_ws, size_t ws_size,
                              hipStream_t stream) {
    const float* h   = (const float*)d_in[0];
    const int*   adj = (const int*)d_in[1];
    const float* z   = (const float*)d_in[2];
    const float* Wp  = (const float*)d_in[3];
    const float* bp  = (const float*)d_in[4];
    const float* Wm  = (const float*)d_in[5];
    const float* bm  = (const float*)d_in[6];
    const float* Wg  = (const float*)d_in[7];
    const float* bg  = (const float*)d_in[8];
    const float* Wk  = (const float*)d_in[9];
    const float* bk  = (const float*)d_in[10];
    const float* Wq  = (const float*)d_in[11];
    const float* bq  = (const float*)d_in[12];
    const float* a   = (const float*)d_in[13];
    float* out = (float*)d_out;

    uint8_t* ws = (uint8_t*)d_ws;
    size_t cur = 0;
    auto alloc = [&](size_t bytes) -> uint8_t* {
        uint8_t* p = ws + cur;
        cur = (cur + bytes + 255) & ~(size_t)255;
        return p;
    };
    uint32_t* maskw  = (uint32_t*)alloc((size_t)cN * 128 * 4);
    float*    h_f32  = (float*)   alloc((size_t)cN * 256 * 4);
    uint16_t* hin_bf = (uint16_t*)alloc((size_t)cN * 256 * 2);
    uint16_t* hcur   = (uint16_t*)alloc((size_t)cN * 256 * 2);
    uint16_t* z_bf   = (uint16_t*)alloc((size_t)cN * 128 * 2);
    uint16_t* WpT    = (uint16_t*)alloc(65536 * 2);
    uint16_t* WmT    = (uint16_t*)alloc((size_t)cL * 65536 * 2);
    uint16_t* WgT    = (uint16_t*)alloc((size_t)cL * 98304 * 2);
    uint16_t* gmT    = (uint16_t*)alloc((size_t)cN * 256 * 2);
    float*    wqv    = (float*)   alloc(cL * 256 * 4);
    float*    wkv    = (float*)   alloc(cL * 256 * 4);
    float*    cvec   = (float*)   alloc(64);
    float*    qq     = (float*)   alloc(cN * 4);
    float*    kk     = (float*)   alloc(cN * 4);
    float4*   stats4 = (float4*)  alloc(cN * 16);
    float*    gsum   = (float*)   alloc(256);
    size_t fixed = cur;
    int nseg = 1;
    if (fixed + 4ull * cN * 256 * 4 <= ws_size) nseg = 4;
    else if (fixed + 2ull * cN * 256 * 4 <= ws_size) nseg = 2;
    float* part = (float*)alloc((size_t)nseg * cN * 256 * 4);

    hipMemsetAsync(gsum, 0, 4, stream);

    int cast_elems = cN * 256 + cN * 128 + 65536 + cL * 65536 + cL * 98304;
    k_cast<<<cast_elems / 256, 256, 0, stream>>>(h, z, Wp, Wm, Wg, hin_bf, z_bf, WpT, WmT, WgT);
    k_bits<<<cN, 256, 0, stream>>>(adj, maskw);
    k_wvec<<<4, 256, 0, stream>>>(Wq, bq, Wk, bk, a, wqv, wkv, cvec);
    k_proj<<<dim3(64, 4), 256, 0, stream>>>(hin_bf, WpT, bp, h_f32, hcur);

    for (int l = 0; l < cL; ++l) {
        k_msgg<<<dim3(64, 4), 256, 0, stream>>>(hcur, z_bf, WmT, WgT, bm, bg, gmT, gsum, l);
        k_qq<<<cN / 256, 256, 0, stream>>>(gmT, wqv, cvec, qq, l);
        k_kk<<<cN / 4, 256, 0, stream>>>(hcur, wkv, cvec, kk, l);
        k_stats<<<cN / 4, 256, 0, stream>>>(qq, kk, maskw, stats4);
        k_agg<<<dim3(cN / 16, nseg), 256, 0, stream>>>(gmT, stats4, maskw, kk, part, nseg);
        k_resid<<<cN * 256 / 4 / 256, 256, 0, stream>>>(part, h_f32, hcur, out, nseg, l == cL - 1 ? 1 : 0);
    }
    k_fin<<<1, 1, 0, stream>>>(gsum, out);
}

// Round 2
// 244.072 us; speedup vs baseline: 1.3393x; 1.3393x over previous
//
#include <hip/hip_runtime.h>
#include <hip/hip_bf16.h>
#include <stdint.h>

static constexpr int cN    = 4096;
static constexpr int cHID  = 256;
static constexpr int cTASK = 128;
static constexpr int cL    = 2;

typedef short bf16x8 __attribute__((ext_vector_type(8)));
typedef float f32x4  __attribute__((ext_vector_type(4)));

#define MFMA(a, b, c) __builtin_amdgcn_mfma_f32_16x16x32_bf16((a), (b), (c), 0, 0, 0)

static __device__ __forceinline__ uint16_t f2bf(float f) {
    uint32_t u = __float_as_uint(f);
    uint32_t r = (u + 0x7FFFu + ((u >> 16) & 1u)) >> 16;
    return (uint16_t)r;
}
static __device__ __forceinline__ float bf2f(uint16_t h) {
    return __uint_as_float(((uint32_t)h) << 16);
}
static __device__ __forceinline__ bf16x8 ld_frag(const uint16_t* p) {
    return *reinterpret_cast<const bf16x8*>(p);
}

// ---------------- simple casts: h, z -> bf16 ----------------
__global__ __launch_bounds__(256) void k_cast(const float* __restrict__ h,
                                              const float* __restrict__ z,
                                              uint16_t* __restrict__ hin_bf,
                                              uint16_t* __restrict__ z_bf) {
    int idx = blockIdx.x * 256 + threadIdx.x;
    if (idx < cN * cHID) { hin_bf[idx] = f2bf(h[idx]); return; }
    idx -= cN * cHID;
    if (idx < cN * cTASK) { z_bf[idx] = f2bf(z[idx]); }
}

// ---------------- tiled transpose-cast: src [L][K][256] f32 -> dst [L][256][K] bf16 ----------------
__global__ __launch_bounds__(256) void k_castT(const float* __restrict__ src,
                                               uint16_t* __restrict__ dst, int K) {
    int l = blockIdx.y;
    int ntk = K / 64;
    int tk = (blockIdx.x % ntk) * 64;
    int td = (blockIdx.x / ntk) * 64;
    __shared__ uint16_t t[64][72];
    const float* S = src + (size_t)l * K * 256;
    uint16_t* D = dst + (size_t)l * 256 * K;
    int lane = threadIdx.x & 63, w = threadIdx.x >> 6;
    for (int r = w; r < 64; r += 4) t[r][lane] = f2bf(S[(size_t)(tk + r) * 256 + td + lane]);
    __syncthreads();
    for (int r = w; r < 64; r += 4) D[(size_t)(td + r) * K + tk + lane] = t[lane][r];
}

// ---------------- adj -> bitmask (2 MiB) ----------------
__global__ __launch_bounds__(256) void k_bits(const int* __restrict__ adj,
                                              uint32_t* __restrict__ maskw) {
    int i = blockIdx.x;
    int wid = threadIdx.x >> 6, lane = threadIdx.x & 63;
    const int* row = adj + (size_t)i * cN;
    for (int base = wid * 64; base < cN; base += 256) {
        int v = row[base + lane];
        unsigned long long b = __ballot(v > 0);
        if (lane == 0)  maskw[i * 128 + (base >> 5)]     = (uint32_t)b;
        if (lane == 32) maskw[i * 128 + (base >> 5) + 1] = (uint32_t)(b >> 32);
    }
}

// ---------------- folded attention vectors (coalesced): wqv = Wq@a_q, wkv = Wk@a_k, consts ----------------
__global__ __launch_bounds__(256) void k_wvec(const float* __restrict__ Wq,
                                              const float* __restrict__ bq,
                                              const float* __restrict__ Wk,
                                              const float* __restrict__ bk,
                                              const float* __restrict__ a,
                                              float* __restrict__ wqv,
                                              float* __restrict__ wkv,
                                              float* __restrict__ cvec) {
    int l = blockIdx.x >> 3, which = (blockIdx.x >> 2) & 1, q = blockIdx.x & 3;
    int tid = threadIdx.x, lane = tid & 63, wid = tid >> 6;
    const float* W    = which ? (Wk + l * 65536) : (Wq + l * 65536);
    const float* avec = a + l * 512 + (which ? 0 : 256);
    __shared__ float av[256];
    __shared__ float red[256];
    av[tid] = avec[tid];
    __syncthreads();
    float av0 = av[lane], av1 = av[64 + lane], av2 = av[128 + lane], av3 = av[192 + lane];
    float* wv = which ? wkv : wqv;
    for (int dd = 0; dd < 16; ++dd) {
        int d = q * 64 + wid * 16 + dd;
        const float* Wr = W + (size_t)d * 256;
        float s = Wr[lane] * av0 + Wr[64 + lane] * av1 + Wr[128 + lane] * av2 + Wr[192 + lane] * av3;
        for (int off = 32; off; off >>= 1) s += __shfl_down(s, off, 64);
        if (lane == 0) wv[l * 256 + d] = s;
    }
    if (q == 0) {
        const float* bias = which ? (bk + l * 256) : (bq + l * 256);
        red[tid] = bias[tid] * av[tid];
        __syncthreads();
        for (int off = 128; off; off >>= 1) {
            if (tid < off) red[tid] += red[tid + off];
            __syncthreads();
        }
        if (tid == 0) cvec[l * 2 + which] = red[0];
    }
}

// ---------------- initial projection: h = hin @ Wp + bp ----------------
__global__ __launch_bounds__(256) void k_proj(const uint16_t* __restrict__ hin_bf,
                                              const uint16_t* __restrict__ WpT,
                                              const float* __restrict__ bp,
                                              float* __restrict__ h_f32,
                                              uint16_t* __restrict__ hcur_bf) {
    int bx = blockIdx.x, by = blockIdx.y;
    int tid = threadIdx.x, lane = tid & 63, wid = tid >> 6;
    int wr = wid >> 1, wc = wid & 1;
    int l16 = lane & 15, g = lane >> 4;
    int i0 = bx * 64 + wr * 32, d0 = by * 64 + wc * 32;
    f32x4 acc[2][2] = {};
#pragma unroll
    for (int ks = 0; ks < 8; ++ks) {
        int kb = ks * 32 + g * 8;
        bf16x8 afr[2], bfr[2];
#pragma unroll
        for (int mr = 0; mr < 2; ++mr) afr[mr] = ld_frag(hin_bf + (size_t)(i0 + mr * 16 + l16) * 256 + kb);
#pragma unroll
        for (int nr = 0; nr < 2; ++nr) bfr[nr] = ld_frag(WpT + (size_t)(d0 + nr * 16 + l16) * 256 + kb);
#pragma unroll
        for (int mr = 0; mr < 2; ++mr)
#pragma unroll
            for (int nr = 0; nr < 2; ++nr)
                acc[mr][nr] = MFMA(afr[mr], bfr[nr], acc[mr][nr]);
    }
#pragma unroll
    for (int mr = 0; mr < 2; ++mr)
#pragma unroll
        for (int nr = 0; nr < 2; ++nr) {
            int d = d0 + nr * 16 + l16;
            float bias = bp[d];
#pragma unroll
            for (int r = 0; r < 4; ++r) {
                int i = i0 + mr * 16 + g * 4 + r;
                float v = acc[mr][nr][r] + bias;
                h_f32[(size_t)i * 256 + d] = v;
                hcur_bf[(size_t)i * 256 + d] = f2bf(v);
            }
        }
}

// ---------------- fused message+gate GEMM + qq/kk GEMVs + gate L1 ----------------
__global__ __launch_bounds__(256) void k_msgg(const uint16_t* __restrict__ hcur_bf,
                                              const uint16_t* __restrict__ z_bf,
                                              const uint16_t* __restrict__ WmT,
                                              const uint16_t* __restrict__ WgT,
                                              const float* __restrict__ bm,
                                              const float* __restrict__ bg,
                                              const float* __restrict__ wqv,
                                              const float* __restrict__ wkv,
                                              const float* __restrict__ cvec,
                                              uint16_t* __restrict__ gmT,
                                              float* __restrict__ qq,
                                              float* __restrict__ kkv,
                                              float* __restrict__ gsum,
                                              int layer) {
    __shared__ float wkv_s[256], wqv_s[256];
    __shared__ float wred[4];
    int tid = threadIdx.x;
    wkv_s[tid] = wkv[layer * 256 + tid];
    wqv_s[tid] = wqv[layer * 256 + tid];
    __syncthreads();

    int bx = blockIdx.x, by = blockIdx.y;
    int lane = tid & 63, wid = tid >> 6;
    int wr = wid >> 1, wc = wid & 1;
    int l16 = lane & 15, g = lane >> 4;
    int i0 = bx * 64 + wr * 32, d0 = by * 64 + wc * 32;
    bool doKK = (by == 0);
    const uint16_t* WmTl = WmT + layer * 65536;
    const uint16_t* WgTl = WgT + layer * 98304;
    f32x4 am[2][2] = {}, ag[2][2] = {};
    float kkp[2] = {0.f, 0.f};
#pragma unroll
    for (int ks = 0; ks < 8; ++ks) {
        int kb = ks * 32 + g * 8;
        bf16x8 afr[2], bmf[2], bgf[2];
#pragma unroll
        for (int mr = 0; mr < 2; ++mr) afr[mr] = ld_frag(hcur_bf + (size_t)(i0 + mr * 16 + l16) * 256 + kb);
#pragma unroll
        for (int nr = 0; nr < 2; ++nr) {
            bmf[nr] = ld_frag(WmTl + (size_t)(d0 + nr * 16 + l16) * 256 + kb);
            bgf[nr] = ld_frag(WgTl + (size_t)(d0 + nr * 16 + l16) * 384 + kb);
        }
        if (doKK) {
#pragma unroll
            for (int mr = 0; mr < 2; ++mr)
#pragma unroll
                for (int u = 0; u < 8; ++u)
                    kkp[mr] += bf2f((uint16_t)afr[mr][u]) * wkv_s[kb + u];
        }
#pragma unroll
        for (int mr = 0; mr < 2; ++mr)
#pragma unroll
            for (int nr = 0; nr < 2; ++nr) {
                am[mr][nr] = MFMA(afr[mr], bmf[nr], am[mr][nr]);
                ag[mr][nr] = MFMA(afr[mr], bgf[nr], ag[mr][nr]);
            }
    }
#pragma unroll
    for (int ks = 0; ks < 4; ++ks) {   // z part of concat: k = 256..383
        int kb = ks * 32 + g * 8;
        bf16x8 afr[2], bgf[2];
#pragma unroll
        for (int mr = 0; mr < 2; ++mr) afr[mr] = ld_frag(z_bf + (size_t)(i0 + mr * 16 + l16) * 128 + kb);
#pragma unroll
        for (int nr = 0; nr < 2; ++nr) bgf[nr] = ld_frag(WgTl + (size_t)(d0 + nr * 16 + l16) * 384 + 256 + kb);
#pragma unroll
        for (int mr = 0; mr < 2; ++mr)
#pragma unroll
            for (int nr = 0; nr < 2; ++nr)
                ag[mr][nr] = MFMA(afr[mr], bgf[nr], ag[mr][nr]);
    }
    float gs = 0.f;
    float qqp[2][4] = {};
#pragma unroll
    for (int mr = 0; mr < 2; ++mr)
#pragma unroll
        for (int nr = 0; nr < 2; ++nr) {
            int d = d0 + nr * 16 + l16;
            float bmv = bm[layer * 256 + d], bgv = bg[layer * 256 + d];
            float wqd = wqv_s[d];
            ushort4 pack;
#pragma unroll
            for (int r = 0; r < 4; ++r) {
                float rm = am[mr][nr][r] + bmv; rm = rm > 0.f ? rm : 0.f;
                float gt = 1.f / (1.f + __expf(-(ag[mr][nr][r] + bgv)));
                gs += gt;
                float gmv = gt * rm;
                qqp[mr][r] += gmv * wqd;
                ((uint16_t*)&pack)[r] = f2bf(gmv);
            }
            int i = i0 + mr * 16 + g * 4;
            *reinterpret_cast<ushort4*>(gmT + (size_t)d * cN + i) = pack;
        }
    // qq: reduce over the 16 l16 lanes (d within this block), atomic across by-blocks
#pragma unroll
    for (int mr = 0; mr < 2; ++mr)
#pragma unroll
        for (int r = 0; r < 4; ++r) {
            float v = qqp[mr][r];
            v += __shfl_xor(v, 1, 64);
            v += __shfl_xor(v, 2, 64);
            v += __shfl_xor(v, 4, 64);
            v += __shfl_xor(v, 8, 64);
            if (l16 == 0) atomicAdd(&qq[i0 + mr * 16 + g * 4 + r], v);
        }
    // kk: complete within by==0 block; fold constants cq + ck
    if (doKK) {
        float cc = cvec[layer * 2 + 0] + cvec[layer * 2 + 1];
#pragma unroll
        for (int mr = 0; mr < 2; ++mr) {
            float v = kkp[mr];
            v += __shfl_xor(v, 16, 64);
            v += __shfl_xor(v, 32, 64);
            if (lane < 16) kkv[i0 + mr * 16 + l16] = v + cc;
        }
    }
    for (int off = 32; off; off >>= 1) gs += __shfl_down(gs, off, 64);
    if (lane == 0) wred[wid] = gs;
    __syncthreads();
    if (tid == 0) atomicAdd(gsum, wred[0] + wred[1] + wred[2] + wred[3]);
}

// ---------------- per-row softmax stats: stats4[i] = (qq, m, 1/den, 0) ----------------
__global__ __launch_bounds__(256) void k_stats(const float* __restrict__ qq,
                                               const float* __restrict__ kkv,
                                               const uint32_t* __restrict__ maskw,
                                               float4* __restrict__ stats4) {
    int wid = threadIdx.x >> 6, lane = threadIdx.x & 63;
    int i = blockIdx.x * 4 + wid;
    float qqi = qq[i];
    const uint32_t* mrow = maskw + i * 128;
    float kmax = -1e30f;
#pragma unroll 4
    for (int c = 0; c < 64; ++c) {
        int j = c * 64 + lane;
        uint32_t w = mrow[j >> 5];
        bool on = (w >> (j & 31)) & 1;
        float kv = kkv[j];
        kmax = (on && kv > kmax) ? kv : kmax;
    }
#pragma unroll
    for (int off = 32; off; off >>= 1) kmax = fmaxf(kmax, __shfl_xor(kmax, off, 64));
    float e0 = qqi + kmax;
    float m = e0 > 0.f ? e0 : 0.01f * e0;
    float den = 0.f;
#pragma unroll 4
    for (int c = 0; c < 64; ++c) {
        int j = c * 64 + lane;
        uint32_t w = mrow[j >> 5];
        bool on = (w >> (j & 31)) & 1;
        float e = qqi + kkv[j];
        e = e > 0.f ? e : 0.01f * e;
        den += on ? __expf(e - m) : 0.f;
    }
#pragma unroll
    for (int off = 32; off; off >>= 1) den += __shfl_xor(den, off, 64);
    if (lane == 0) {
        float rden = den > 0.f ? 1.f / den : 0.f;
        stats4[i] = make_float4(qqi, m, rden, 0.f);
    }
}

// ---------------- agg = attention^T @ gm, pipelined, j-tile = MR*16, 8 waves split d ----------------
template <int MR>
__global__ __launch_bounds__(512, 4) void k_agg(const uint16_t* __restrict__ gmT,
                                                const float4* __restrict__ stats4,
                                                const uint32_t* __restrict__ maskw,
                                                const float* __restrict__ kkv,
                                                float* __restrict__ part, int nseg) {
    constexpr int JT = MR * 16;       // j-tile width
    constexpr int WPT = MR * 4;       // w values per thread per stage (JT*128/512)
    constexpr int ASTR = 136;         // LDS row stride (bf16 elems), conflict-free b128
    __shared__ uint16_t A_lds[2][JT * ASTR];
    int jt0 = blockIdx.x * JT, seg = blockIdx.y;
    int tid = threadIdx.x, lane = tid & 63, wid = tid >> 6;
    int l16 = lane & 15, g = lane >> 4;
    int jj = tid & (JT - 1);
    int ig0 = (tid / JT) * WPT;
    float kkj = kkv[jt0 + jj];
    int wbase = (jt0 >> 5) + (jj >> 5);
    int shift = jj & 31;
    f32x4 acc[MR][2] = {};
    int kseg = cN / nseg;
    int ib0 = seg * kseg;
    int nstg = kseg / 128;

    auto wcompute = [&](int s, int b) {
        int ibase = ib0 + s * 128;
        uint16_t* dst = &A_lds[b][jj * ASTR + ig0];
#pragma unroll
        for (int c = 0; c < WPT / 8; ++c) {
            uint16_t wb[8];
#pragma unroll
            for (int u = 0; u < 8; ++u) {
                int i = ibase + ig0 + c * 8 + u;
                float4 st = stats4[i];
                uint32_t wrd = maskw[i * 128 + wbase];
                bool on = (wrd >> shift) & 1;
                float e = st.x + kkj;
                e = e > 0.f ? e : 0.01f * e;
                float w = on ? __expf(e - st.y) * st.z : 0.f;
                wb[u] = f2bf(w);
            }
            *reinterpret_cast<uint4*>(dst + c * 8) = *reinterpret_cast<uint4*>(wb);
        }
    };

    wcompute(0, 0);
    __syncthreads();
    for (int s = 0; s < nstg; ++s) {
        int ibase = ib0 + s * 128;
        if (s + 1 < nstg) wcompute(s + 1, (s + 1) & 1);
        const uint16_t* Ab = A_lds[s & 1];
#pragma unroll
        for (int ksub = 0; ksub < 4; ++ksub) {
            int kb = ksub * 32 + g * 8;
            int ic = ibase + kb;
            bf16x8 bfr[2];
#pragma unroll
            for (int nr = 0; nr < 2; ++nr)
                bfr[nr] = ld_frag(gmT + (size_t)(wid * 32 + nr * 16 + l16) * cN + ic);
#pragma unroll
            for (int mr = 0; mr < MR; ++mr) {
                bf16x8 afr = ld_frag(&Ab[(mr * 16 + l16) * ASTR + kb]);
                acc[mr][0] = MFMA(afr, bfr[0], acc[mr][0]);
                acc[mr][1] = MFMA(afr, bfr[1], acc[mr][1]);
            }
        }
        __syncthreads();
    }
#pragma unroll
    for (int mr = 0; mr < MR; ++mr)
#pragma unroll
        for (int nr = 0; nr < 2; ++nr) {
            int d = wid * 32 + nr * 16 + l16;
#pragma unroll
            for (int r = 0; r < 4; ++r) {
                int j = jt0 + mr * 16 + g * 4 + r;
                part[((size_t)seg * cN + j) * 256 + d] = acc[mr][nr][r];
            }
        }
}

// ---------------- residual: h = (sum(parts) + h)/2 ----------------
__global__ __launch_bounds__(256) void k_resid(const float* __restrict__ part,
                                               float* __restrict__ h_f32,
                                               uint16_t* __restrict__ hcur_bf,
                                               float* __restrict__ out,
                                               int nseg, int last) {
    int idx = blockIdx.x * 256 + threadIdx.x;
    float4 acc = reinterpret_cast<float4*>(h_f32)[idx];
    for (int p = 0; p < nseg; ++p) {
        float4 v = reinterpret_cast<const float4*>(part + (size_t)p * cN * 256)[idx];
        acc.x += v.x; acc.y += v.y; acc.z += v.z; acc.w += v.w;
    }
    acc.x *= 0.5f; acc.y *= 0.5f; acc.z *= 0.5f; acc.w *= 0.5f;
    reinterpret_cast<float4*>(h_f32)[idx] = acc;
    ushort4 hb; hb.x = f2bf(acc.x); hb.y = f2bf(acc.y); hb.z = f2bf(acc.z); hb.w = f2bf(acc.w);
    reinterpret_cast<ushort4*>(hcur_bf)[idx] = hb;
    if (last) reinterpret_cast<float4*>(out)[idx] = acc;
}

__global__ void k_fin(const float* __restrict__ gsum, float* __restrict__ out) {
    out[(size_t)cN * cHID] = gsum[0] * (1.f / ((float)(cN * cHID) * (float)cL));
}

// ---------------- host side ----------------
extern "C" void kernel_launch(void* const* d_in, const int* in_sizes, int n_in,
                              void* d_out, int out_size, void* d_ws, size_t ws_size,
                              hipStream_t stream) {
    const float* h   = (const float*)d_in[0];
    const int*   adj = (const int*)d_in[1];
    const float* z   = (const float*)d_in[2];
    const float* Wp  = (const float*)d_in[3];
    const float* bp  = (const float*)d_in[4];
    const float* Wm  = (const float*)d_in[5];
    const float* bm  = (const float*)d_in[6];
    const float* Wg  = (const float*)d_in[7];
    const float* bg  = (const float*)d_in[8];
    const float* Wk  = (const float*)d_in[9];
    const float* bk  = (const float*)d_in[10];
    const float* Wq  = (const float*)d_in[11];
    const float* bq  = (const float*)d_in[12];
    const float* a   = (const float*)d_in[13];
    float* out = (float*)d_out;

    uint8_t* ws = (uint8_t*)d_ws;
    size_t cur = 0;
    auto alloc = [&](size_t bytes) -> uint8_t* {
        uint8_t* p = ws + cur;
        cur = (cur + bytes + 255) & ~(size_t)255;
        return p;
    };
    uint32_t* maskw  = (uint32_t*)alloc((size_t)cN * 128 * 4);
    float*    h_f32  = (float*)   alloc((size_t)cN * 256 * 4);
    uint16_t* hin_bf = (uint16_t*)alloc((size_t)cN * 256 * 2);
    uint16_t* hcur   = (uint16_t*)alloc((size_t)cN * 256 * 2);
    uint16_t* z_bf   = (uint16_t*)alloc((size_t)cN * 128 * 2);
    uint16_t* WpT    = (uint16_t*)alloc(65536 * 2);
    uint16_t* WmT    = (uint16_t*)alloc((size_t)cL * 65536 * 2);
    uint16_t* WgT    = (uint16_t*)alloc((size_t)cL * 98304 * 2);
    uint16_t* gmT    = (uint16_t*)alloc((size_t)cN * 256 * 2);
    float*    wqv    = (float*)   alloc(cL * 256 * 4);
    float*    wkv    = (float*)   alloc(cL * 256 * 4);
    float*    cvec   = (float*)   alloc(256);
    float*    qq     = (float*)   alloc(cN * 4);
    float*    kk     = (float*)   alloc(cN * 4);
    float4*   stats4 = (float4*)  alloc(cN * 16);
    float*    gsum   = (float*)   alloc(256);
    size_t fixed = cur;
    const size_t seg_bytes = (size_t)cN * 256 * 4;
    int nseg;
    if      (fixed + 8 * seg_bytes <= ws_size) nseg = 8;
    else if (fixed + 4 * seg_bytes <= ws_size) nseg = 4;
    else if (fixed + 2 * seg_bytes <= ws_size) nseg = 2;
    else nseg = 1;
    float* part = (float*)alloc((size_t)nseg * seg_bytes);

    hipMemsetAsync(gsum, 0, 4, stream);

    int cast_elems = cN * 256 + cN * 128;
    k_cast<<<(cast_elems + 255) / 256, 256, 0, stream>>>(h, z, hin_bf, z_bf);
    k_castT<<<dim3(16, 1), 256, 0, stream>>>(Wp, WpT, 256);
    k_castT<<<dim3(16, cL), 256, 0, stream>>>(Wm, WmT, 256);
    k_castT<<<dim3(24, cL), 256, 0, stream>>>(Wg, WgT, 384);
    k_bits<<<cN, 256, 0, stream>>>(adj, maskw);
    k_wvec<<<16, 256, 0, stream>>>(Wq, bq, Wk, bk, a, wqv, wkv, cvec);
    k_proj<<<dim3(64, 4), 256, 0, stream>>>(hin_bf, WpT, bp, h_f32, hcur);

    for (int l = 0; l < cL; ++l) {
        hipMemsetAsync(qq, 0, cN * 4, stream);
        k_msgg<<<dim3(64, 4), 256, 0, stream>>>(hcur, z_bf, WmT, WgT, bm, bg,
                                                wqv, wkv, cvec, gmT, qq, kk, gsum, l);
        k_stats<<<cN / 4, 256, 0, stream>>>(qq, kk, maskw, stats4);
        if (nseg == 8)
            k_agg<4><<<dim3(cN / 64, 8), 512, 0, stream>>>(gmT, stats4, maskw, kk, part, 8);
        else
            k_agg<2><<<dim3(cN / 32, nseg), 512, 0, stream>>>(gmT, stats4, maskw, kk, part, nseg);
        k_resid<<<cN * 256 / 4 / 256, 256, 0, stream>>>(part, h_f32, hcur, out, nseg, l == cL - 1 ? 1 : 0);
    }
    k_fin<<<1, 1, 0, stream>>>(gsum, out);
}